// Round 13
// baseline (453.826 us; speedup 1.0000x reference)
//
#include <hip/hip_runtime.h>

#define TSTEPS 48
#define OUT_STEPS 24
#define L2E 1.44269504088896340736f
#define ECLAMP 30.0f

typedef short bf16x8 __attribute__((ext_vector_type(8)));
typedef float f32x4 __attribute__((ext_vector_type(4)));

// RNE bf16 hi + truncated-residual lo (weights; off hot path).
__device__ __forceinline__ void bf_split_rne(float f, short& hi, short& lo) {
    unsigned u = __builtin_bit_cast(unsigned, f);
    unsigned r = u + 0x7FFFu + ((u >> 16) & 1u);
    unsigned short hb = (unsigned short)(r >> 16);
    float hif = __builtin_bit_cast(float, (unsigned)hb << 16);
    float lof = f - hif;
    unsigned short lb = (unsigned short)(__builtin_bit_cast(unsigned, lof) >> 16);
    hi = (short)hb; lo = (short)lb;
}

// Per-tile exp2 pre-scale: gates i,f,o get -log2e; gate g (tiles 4,5) -2*log2e.
__device__ __forceinline__ float tile_scale(int t) {
    return (t == 4 || t == 5) ? (-2.0f * L2E) : (-L2E);
}

// A-fragments of PRE-SCALED permuted U^T (hi/lo split), register-resident,
// SHARED by both pipeline groups. (R11 verbatim.)
__device__ __forceinline__ void load_Ufrags(const float* __restrict__ Uk,
                                            bf16x8* Ahi, bf16x8* Alo, int LQ, int LC) {
    const int ulo = ((LC >> 2) << 3) + (LC & 3);
#pragma unroll
    for (int t = 0; t < 8; ++t) {
        const float s = tile_scale(t);
        const int col = (t >> 1) * 32 + ulo + (t & 1) * 4;
        bf16x8 ah, al;
#pragma unroll
        for (int j = 0; j < 8; ++j) {
            float w = Uk[(LQ * 8 + j) * 128 + col] * s;
            short hb, lb; bf_split_rne(w, hb, lb);
            ah[j] = hb; al[j] = lb;
        }
        Ahi[t] = ah; Alo[t] = al;
    }
}

// Issue one group's full MFMA block (8 tiles, acc stays live while the OTHER
// group's activation runs on VALU — in-wave software pipelining).
__device__ __forceinline__ void mfma_group(float x,
    const bf16x8* Ahi, const bf16x8* Alo,
    const float* __restrict__ wkb_cell,
    const bf16x8 h_hi, const bf16x8 h_lo, f32x4* acc, int LQ) {
#pragma unroll
    for (int t = 0; t < 8; ++t) {
        const float* wb = wkb_cell + (t * 4 + LQ) * 8;
        f32x4 wk = *(const f32x4*)wb;         // ds_read_b128 (quad-broadcast)
        f32x4 bb = *(const f32x4*)(wb + 4);   // ds_read_b128
        f32x4 a;
#pragma unroll
        for (int r = 0; r < 4; ++r) a[r] = __builtin_fmaf(x, wk[r], bb[r]);
        a = __builtin_amdgcn_mfma_f32_16x16x32_bf16(Alo[t], h_hi, a, 0, 0, 0);
        a = __builtin_amdgcn_mfma_f32_16x16x32_bf16(Ahi[t], h_lo, a, 0, 0, 0);
        a = __builtin_amdgcn_mfma_f32_16x16x32_bf16(Ahi[t], h_hi, a, 0, 0, 0);
        acc[t] = a;
    }
}

// Activation for one group — VERBATIM R11 scalar math (absmax 4.88e-4).
// acc indexed by tile: gates (i,f,g,o) = acc[tl], acc[2+tl], acc[4+tl], acc[6+tl].
template <bool NEED_P>
__device__ __forceinline__ float act_group(const f32x4* acc,
    bf16x8& h_hi, bf16x8& h_lo, float* cs, const float* wdv) {
    float pp = 0.0f;
    bf16x8 nhh, nhl;
#pragma unroll
    for (int tl = 0; tl < 2; ++tl) {
#pragma unroll
        for (int r = 0; r < 4; ++r) {
            const int j = tl * 4 + r;
            float ei = __builtin_amdgcn_exp2f(acc[0 + tl][r]);
            float ef = __builtin_amdgcn_exp2f(acc[2 + tl][r]);
            float eg = __builtin_amdgcn_exp2f(__builtin_fminf(acc[4 + tl][r], ECLAMP));
            float eo = __builtin_amdgcn_exp2f(acc[6 + tl][r]);
            float di = 1.0f + ei, df = 1.0f + ef, dg = 1.0f + eg, do_ = 1.0f + eo;
            float ngs = __builtin_fmaf(eg, 2.0f * L2E, -2.0f * L2E);  // -2L2E*(1-eg)
            float t1 = di * dg;
            float t2 = cs[j] * t1;
            float num = __builtin_fmaf(ngs, df, t2);
            float cn = num * __builtin_amdgcn_rcpf(df * t1);          // scaled c'
            cs[j] = cn;
            float ec = __builtin_amdgcn_exp2f(__builtin_fminf(cn, ECLAMP)); // e^-2c
            float h = (1.0f - ec) * __builtin_amdgcn_rcpf(do_ * (1.0f + ec)); // o*tanh(c)
            if constexpr (NEED_P) pp = __builtin_fmaf(h, wdv[j], pp);
            unsigned u = __builtin_bit_cast(unsigned, h);
            float hif = __builtin_bit_cast(float, u & 0xFFFF0000u);
            float lof = h - hif;
            nhh[j] = (short)(u >> 16);
            nhl[j] = (short)(__builtin_bit_cast(unsigned, lof) >> 16);
        }
    }
    h_hi = nhh;
    h_lo = nhl;
    return pp;
}

// (256,2): ~190 VGPR demand -> 2 waves/SIMD, no spill. The win comes from
// in-wave 2-group pipelining, not occupancy (R8/R12: VALU idles 33% waiting
// on the serial MFMA->act->MFMA chain; groups break the serialization).
__global__ __launch_bounds__(256, 2) void lstm_feedback_mfma11(
    const float* __restrict__ inputs,  // [B, 48]
    const float* __restrict__ Wk_w, const float* __restrict__ Uk_w, const float* __restrict__ b_w,
    const float* __restrict__ Wk_d, const float* __restrict__ Uk_d, const float* __restrict__ b_d,
    const float* __restrict__ Wd, const float* __restrict__ bd,
    float* __restrict__ out,           // [B, 24]
    int B) {
    const int tid = threadIdx.x;       // 4 waves x 2 groups x 16 batch = 128 batch/block
    const int w = tid >> 6;
    const int lane = tid & 63;
    const int LQ = lane >> 4;
    const int LC = lane & 15;
    const int mblk = blockIdx.x * 128;

    __shared__ float xbuf[4][2][16 * 49];    // [wave][group][batch x step], stride 49
    __shared__ float predbuf[4][2][16 * 25]; // stride 25
    __shared__ __align__(16) float wkb[2][8][4][8];  // [cell][tile][LQ][wk0..3,b0..3]

    // Stage BOTH cells' pre-scaled Wk/b (R11 verbatim).
    {
        const int cell = tid >> 7, t = (tid >> 4) & 7, q = (tid >> 2) & 3, r = tid & 3;
        const float* Wks = cell ? Wk_d : Wk_w;
        const float* bvs = cell ? b_d : b_w;
        const float s = tile_scale(t);
        const int colb = (t >> 1) * 32 + q * 8 + (t & 1) * 4 + r;
        wkb[cell][t][q][r]     = Wks[colb] * s;
        wkb[cell][t][q][4 + r] = bvs[colb] * s;
    }

    // Block cooperatively loads its 128x48 input tile (coalesced).
    for (int i = tid; i < 128 * TSTEPS; i += 256) {
        int m = i / TSTEPS, t = i - m * TSTEPS;
        xbuf[m >> 5][(m >> 4) & 1][(m & 15) * 49 + t] = inputs[(long)mblk * TSTEPS + i];
    }

    bf16x8 Ahi[8], Alo[8];
    load_Ufrags(Uk_w, Ahi, Alo, LQ, LC);

    bf16x8 h0h = {0,0,0,0,0,0,0,0}, h0l = h0h, h1h = h0h, h1l = h0h;
    float cs0[8] = {0,0,0,0,0,0,0,0}, cs1[8] = {0,0,0,0,0,0,0,0};
    f32x4 acc0[8], acc1[8];

    __syncthreads();  // xbuf + wkb visible

    const float* __restrict__ x0 = &xbuf[w][0][LC * 49];
    const float* __restrict__ x1 = &xbuf[w][1][LC * 49];
    const float* __restrict__ wkb_w = &wkb[0][0][0][0];
    const float* __restrict__ wkb_d = &wkb[1][0][0][0];

    // ---- pipelined warmup ----
    // Schedule: mfma(G1,t) | act(G0,t) | mfma(G0,t+1) | act(G1,t): each act
    // runs while the other group's MFMAs execute in the background.
    mfma_group(x0[0], Ahi, Alo, wkb_w, h0h, h0l, acc0, LQ);
    for (int t = 0; t < TSTEPS - 1; ++t) {
        asm volatile("" ::: "memory");  // keep wkb/x ds_reads in-loop
        mfma_group(x1[t], Ahi, Alo, wkb_w, h1h, h1l, acc1, LQ);
        act_group<false>(acc0, h0h, h0l, cs0, nullptr);
        mfma_group(x0[t + 1], Ahi, Alo, wkb_w, h0h, h0l, acc0, LQ);
        act_group<false>(acc1, h1h, h1l, cs1, nullptr);
    }
    // In flight: acc0 = G0 step 47. G1 acts done through step 46.

    float wdv[8];
#pragma unroll
    for (int j = 0; j < 8; ++j) wdv[j] = Wd[LQ * 8 + j];
    const float bdv = bd[0];

    mfma_group(x1[TSTEPS - 1], Ahi, Alo, wkb_w, h1h, h1l, acc1, LQ);  // G1 step 47

    float p0 = act_group<true>(acc0, h0h, h0l, cs0, wdv);
    p0 += __shfl_xor(p0, 16); p0 += __shfl_xor(p0, 32); p0 += bdv;
    if (LQ == 0) predbuf[w][0][LC * 25 + 0] = p0;

    // Swap to decode weights (acc1's warmup MFMAs already issued).
    load_Ufrags(Uk_d, Ahi, Alo, LQ, LC);

    mfma_group(p0, Ahi, Alo, wkb_d, h0h, h0l, acc0, LQ);  // G0 decode s=1

    float p1 = act_group<true>(acc1, h1h, h1l, cs1, wdv);
    p1 += __shfl_xor(p1, 16); p1 += __shfl_xor(p1, 32); p1 += bdv;
    if (LQ == 0) predbuf[w][1][LC * 25 + 0] = p1;

    // ---- pipelined decode ----
    for (int s = 1; s < OUT_STEPS; ++s) {
        asm volatile("" ::: "memory");
        mfma_group(p1, Ahi, Alo, wkb_d, h1h, h1l, acc1, LQ);   // G1 decode s
        p0 = act_group<true>(acc0, h0h, h0l, cs0, wdv);
        p0 += __shfl_xor(p0, 16); p0 += __shfl_xor(p0, 32); p0 += bdv;
        if (LQ == 0) predbuf[w][0][LC * 25 + s] = p0;
        if (s < OUT_STEPS - 1)
            mfma_group(p0, Ahi, Alo, wkb_d, h0h, h0l, acc0, LQ);  // G0 decode s+1
        p1 = act_group<true>(acc1, h1h, h1l, cs1, wdv);
        p1 += __shfl_xor(p1, 16); p1 += __shfl_xor(p1, 32); p1 += bdv;
        if (LQ == 0) predbuf[w][1][LC * 25 + s] = p1;
    }

    // ---- coalesced output flush ----
    __syncthreads();
    for (int i = tid; i < 128 * OUT_STEPS; i += 256) {
        int m = i / OUT_STEPS, s = i - m * OUT_STEPS;
        out[(long)mblk * OUT_STEPS + i] = predbuf[m >> 5][(m >> 4) & 1][(m & 15) * 25 + s];
    }
}

extern "C" void kernel_launch(void* const* d_in, const int* in_sizes, int n_in,
                              void* d_out, int out_size, void* d_ws, size_t ws_size,
                              hipStream_t stream) {
    const float* inputs = (const float*)d_in[0];
    const float* Wk_w   = (const float*)d_in[1];
    const float* Uk_w   = (const float*)d_in[2];
    const float* b_w    = (const float*)d_in[3];
    const float* Wk_d   = (const float*)d_in[4];
    const float* Uk_d   = (const float*)d_in[5];
    const float* b_d    = (const float*)d_in[6];
    const float* Wd     = (const float*)d_in[7];
    const float* bd     = (const float*)d_in[8];
    float* out = (float*)d_out;

    const int B = in_sizes[0] / TSTEPS;
    const int grid = (B + 127) / 128;  // 128 batch rows per 256-thread block
    lstm_feedback_mfma11<<<grid, 256, 0, stream>>>(
        inputs, Wk_w, Uk_w, b_w, Wk_d, Uk_d, b_d, Wd, bd, out, B);
}

// Round 14
// 420.104 us; speedup vs baseline: 1.0803x; 1.0803x over previous
//
#include <hip/hip_runtime.h>

#define TSTEPS 48
#define OUT_STEPS 24
#define L2E 1.44269504088896340736f
#define ECLAMP 30.0f

typedef short bf16x8 __attribute__((ext_vector_type(8)));
typedef float f32x4 __attribute__((ext_vector_type(4)));
typedef float f32x16 __attribute__((ext_vector_type(16)));
typedef unsigned int u32x4 __attribute__((ext_vector_type(4)));

// RNE bf16 hi + truncated-residual lo (weights; off hot path).
__device__ __forceinline__ void bf_split_rne(float f, short& hi, short& lo) {
    unsigned u = __builtin_bit_cast(unsigned, f);
    unsigned r = u + 0x7FFFu + ((u >> 16) & 1u);
    unsigned short hb = (unsigned short)(r >> 16);
    float hif = __builtin_bit_cast(float, (unsigned)hb << 16);
    float lof = f - hif;
    unsigned short lb = (unsigned short)(__builtin_bit_cast(unsigned, lof) >> 16);
    hi = (short)hb; lo = (short)lb;
}

// Truncation split packed into one dword: low16 = hi-bf16, high16 = lo-bf16.
__device__ __forceinline__ unsigned split_pack(float f) {
    unsigned u = __builtin_bit_cast(unsigned, f);
    float hif = __builtin_bit_cast(float, u & 0xFFFF0000u);
    float lof = f - hif;
    unsigned lo = __builtin_bit_cast(unsigned, lof);
    return (u >> 16) | (lo & 0xFFFF0000u);
}

// Gate pre-scale for exp2: i,f,o -> -log2e; g (gate 2) -> -2*log2e.
__device__ __forceinline__ float gate_scale(int g) {
    return (g == 2) ? (-2.0f * L2E) : (-L2E);
}

// A-fragments of pre-scaled U^T for 32x32x16 tiles, tile = whole gate.
// Lane: m = lane&31 (out-unit within gate), H = lane>>5; elem j of K-half c:
// in-unit = 16c+4H+(j&3)+8*(j>>2). (R12 verbatim — verified.)
__device__ __forceinline__ void load_Ufrags32(const float* __restrict__ Uk,
                                              bf16x8 Ahi[4][2], bf16x8 Alo[4][2],
                                              int m, int H) {
#pragma unroll
    for (int g = 0; g < 4; ++g) {
        const float s = gate_scale(g);
#pragma unroll
        for (int c = 0; c < 2; ++c) {
            bf16x8 ah, al;
#pragma unroll
            for (int j = 0; j < 8; ++j) {
                const int uin = 16 * c + 4 * H + (j & 3) + 8 * (j >> 2);
                float w = Uk[uin * 128 + g * 32 + m] * s;
                short hb, lb; bf_split_rne(w, hb, lb);
                ah[j] = hb; al[j] = lb;
            }
            Ahi[g][c] = ah; Alo[g][c] = al;
        }
    }
}

// One LSTM step for 32 batch rows. h enters/exits as two K-half B-frags
// (identity repack). A4 acc-init operands come from LDS (loop-invariant,
// kept off the register file — R12 spilled ~50 MB with them in VGPRs).
// Activation math VERBATIM from the verified scalar form (absmax 4.88e-4).
template <bool NEED_P>
__device__ __forceinline__ float lstm_step32(unsigned xpack,
    const bf16x8 Ahi[4][2], const bf16x8 Alo[4][2],
    const short* __restrict__ a4cell,          // &a4lds[cell][0][0]
    bf16x8& B0h, bf16x8& B0l, bf16x8& B1h, bf16x8& B1l,
    float* cs, const float* __restrict__ wdp,  // &wdlds[H][0] (broadcast)
    int lane, int H) {
    // B4 on H==0 lanes: [x_hi, x_lo, x_hi, 1, 1, 0,0,0].
    unsigned w0 = xpack;
    unsigned w1 = (xpack & 0xFFFFu) | 0x3F800000u;
    unsigned w2 = 0x00003F80u;
    if (H != 0) { w0 = 0u; w1 = 0u; w2 = 0u; }
    u32x4 b4u = {w0, w1, w2, 0u};
    const bf16x8 B4 = __builtin_bit_cast(bf16x8, b4u);
    const f32x16 zero16 = {0,0,0,0,0,0,0,0,0,0,0,0,0,0,0,0};

    f32x16 acc[4];
#pragma unroll
    for (int g = 0; g < 4; ++g) {
        const bf16x8 A4g = *(const bf16x8*)(a4cell + (g * 64 + lane) * 8);
        f32x16 a = __builtin_amdgcn_mfma_f32_32x32x16_bf16(A4g, B4, zero16, 0, 0, 0);
        a = __builtin_amdgcn_mfma_f32_32x32x16_bf16(Alo[g][0], B0h, a, 0, 0, 0);
        a = __builtin_amdgcn_mfma_f32_32x32x16_bf16(Ahi[g][0], B0l, a, 0, 0, 0);
        a = __builtin_amdgcn_mfma_f32_32x32x16_bf16(Ahi[g][0], B0h, a, 0, 0, 0);
        a = __builtin_amdgcn_mfma_f32_32x32x16_bf16(Alo[g][1], B1h, a, 0, 0, 0);
        a = __builtin_amdgcn_mfma_f32_32x32x16_bf16(Ahi[g][1], B1l, a, 0, 0, 0);
        a = __builtin_amdgcn_mfma_f32_32x32x16_bf16(Ahi[g][1], B1h, a, 0, 0, 0);
        acc[g] = a;
    }

    float pp = 0.0f;
    bf16x8 n0h, n0l, n1h, n1l;
#pragma unroll
    for (int r = 0; r < 16; ++r) {
        float ei = __builtin_amdgcn_exp2f(acc[0][r]);
        float ef = __builtin_amdgcn_exp2f(acc[1][r]);
        float eg = __builtin_amdgcn_exp2f(__builtin_fminf(acc[2][r], ECLAMP));
        float eo = __builtin_amdgcn_exp2f(acc[3][r]);
        float di = 1.0f + ei, df = 1.0f + ef, dg = 1.0f + eg, do_ = 1.0f + eo;
        float ngs = __builtin_fmaf(eg, 2.0f * L2E, -2.0f * L2E);  // -2L2E*(1-eg)
        float t1 = di * dg;
        float t2 = cs[r] * t1;
        float num = __builtin_fmaf(ngs, df, t2);
        float cn = num * __builtin_amdgcn_rcpf(df * t1);          // scaled c'
        cs[r] = cn;
        float ec = __builtin_amdgcn_exp2f(__builtin_fminf(cn, ECLAMP)); // e^-2c
        float h = (1.0f - ec) * __builtin_amdgcn_rcpf(do_ * (1.0f + ec)); // o*tanh(c)
        if constexpr (NEED_P) pp = __builtin_fmaf(h, wdp[r], pp); // LDS broadcast
        unsigned u = __builtin_bit_cast(unsigned, h);
        float hif = __builtin_bit_cast(float, u & 0xFFFF0000u);
        float lof = h - hif;
        short hb = (short)(u >> 16);
        short lb = (short)(__builtin_bit_cast(unsigned, lof) >> 16);
        if (r < 8) { n0h[r] = hb; n0l[r] = lb; }
        else       { n1h[r - 8] = hb; n1l[r - 8] = lb; }
    }
    B0h = n0h; B0l = n0l; B1h = n1h; B1l = n1l;
    return pp;
}

// (256,2). Arch-VGPR demand after moving A4/wdv to LDS: ~116 < 128 -> no
// scratch spill (R12 wrote ~50 MB of scratch with them register-resident).
__global__ __launch_bounds__(256, 2) void lstm_feedback_mfma12(
    const float* __restrict__ inputs,  // [B, 48]
    const float* __restrict__ Wk_w, const float* __restrict__ Uk_w, const float* __restrict__ b_w,
    const float* __restrict__ Wk_d, const float* __restrict__ Uk_d, const float* __restrict__ b_d,
    const float* __restrict__ Wd, const float* __restrict__ bd,
    float* __restrict__ out,           // [B, 24]
    int B) {
    const int tid = threadIdx.x;       // 4 waves x 32 batch = 128 batch/block
    const int w = tid >> 6;
    const int lane = tid & 63;
    const int m = lane & 31;           // batch column within wave / out-unit row
    const int H = lane >> 5;
    const int mblk = blockIdx.x * 128;

    __shared__ float xbuf[4][32 * 49];     // stride 49: conflict-free, H-broadcast
    __shared__ float predbuf[4][32 * 25];
    __shared__ __align__(16) short a4lds[2 * 4 * 64 * 8];  // [cell][gate][lane] bf16x8
    __shared__ float wdlds[2][16];                         // [H][r] Wd in D-reg order

    // Block cooperatively loads its 128x48 input tile (coalesced).
    for (int i = tid; i < 128 * TSTEPS; i += 256) {
        int mb = i / TSTEPS, t = i - mb * TSTEPS;
        xbuf[mb >> 5][(mb & 31) * 49 + t] = inputs[(long)mblk * TSTEPS + i];
    }

    // Stage A4 for both cells: waves 0/1 each build their lane's operand.
    // A4[g] = [wk_hi, wk_hi, wk_lo, b_hi, b_lo, 0,0,0] (H==0 lanes), else 0.
    if (w < 2) {
        const float* Wks = w ? Wk_d : Wk_w;
        const float* bvs = w ? b_d : b_w;
#pragma unroll
        for (int g = 0; g < 4; ++g) {
            const float s = gate_scale(g);
            short whi, wlo, bhi, blo;
            bf_split_rne(Wks[g * 32 + m] * s, whi, wlo);
            bf_split_rne(bvs[g * 32 + m] * s, bhi, blo);
            bf16x8 a = {whi, whi, wlo, bhi, blo, 0, 0, 0};
            u32x4 z4 = {0u, 0u, 0u, 0u};
            if (H != 0) a = __builtin_bit_cast(bf16x8, z4);
            *(bf16x8*)(a4lds + ((w * 4 + g) * 64 + lane) * 8) = a;
        }
    }
    // Stage Wd in D-layout order: unit of D reg r is (r&3) + 8*(r>>2) + 4H.
    if (tid < 32) {
        const int r = tid & 15, Hh = tid >> 4;
        wdlds[Hh][r] = Wd[(r & 3) + 8 * (r >> 2) + 4 * Hh];
    }

    bf16x8 Ahi[4][2], Alo[4][2];
    load_Ufrags32(Uk_w, Ahi, Alo, m, H);

    u32x4 z4 = {0u, 0u, 0u, 0u};
    bf16x8 B0h = __builtin_bit_cast(bf16x8, z4), B0l = B0h, B1h = B0h, B1l = B0h;
    float cs[16];
#pragma unroll
    for (int r = 0; r < 16; ++r) cs[r] = 0.0f;

    __syncthreads();  // xbuf + a4lds + wdlds visible

    const float* __restrict__ xcol = &xbuf[w][m * 49];
    const short* __restrict__ a4_w = a4lds;
    const short* __restrict__ a4_d = a4lds + 4 * 64 * 8;
    const float* __restrict__ wdp = &wdlds[H][0];

    // ---- warmup: steps 0..46 (pred fold compiled out) ----
    for (int t = 0; t < TSTEPS - 1; ++t) {
        asm volatile("" ::: "memory");  // keep a4lds reads in-loop (anti-LICM)
        lstm_step32<false>(split_pack(xcol[t]), Ahi, Alo, a4_w,
                           B0h, B0l, B1h, B1l, cs, wdp, lane, H);
    }

    const float bdv = bd[0];

    // ---- last warmup step with pred fold; single-shuffle reduce ----
    asm volatile("" ::: "memory");
    float p = lstm_step32<true>(split_pack(xcol[TSTEPS - 1]), Ahi, Alo, a4_w,
                                B0h, B0l, B1h, B1l, cs, wdp, lane, H);
    p += __shfl_xor(p, 32);
    p += bdv;                          // both H lanes of batch m hold pred(batch m)
    if (H == 0) predbuf[w][m * 25 + 0] = p;

    // ---- decode weights (A4 for decode already staged) ----
    load_Ufrags32(Uk_d, Ahi, Alo, m, H);

    for (int s = 1; s < OUT_STEPS; ++s) {
        asm volatile("" ::: "memory");
        p = lstm_step32<true>(split_pack(p), Ahi, Alo, a4_d,
                              B0h, B0l, B1h, B1l, cs, wdp, lane, H);
        p += __shfl_xor(p, 32);
        p += bdv;
        if (H == 0) predbuf[w][m * 25 + s] = p;
    }

    // ---- coalesced output flush ----
    __syncthreads();
    for (int i = tid; i < 128 * OUT_STEPS; i += 256) {
        int mb = i / OUT_STEPS, s = i - mb * OUT_STEPS;
        out[(long)mblk * OUT_STEPS + i] = predbuf[mb >> 5][(mb & 31) * 25 + s];
    }
}

extern "C" void kernel_launch(void* const* d_in, const int* in_sizes, int n_in,
                              void* d_out, int out_size, void* d_ws, size_t ws_size,
                              hipStream_t stream) {
    const float* inputs = (const float*)d_in[0];
    const float* Wk_w   = (const float*)d_in[1];
    const float* Uk_w   = (const float*)d_in[2];
    const float* b_w    = (const float*)d_in[3];
    const float* Wk_d   = (const float*)d_in[4];
    const float* Uk_d   = (const float*)d_in[5];
    const float* b_d    = (const float*)d_in[6];
    const float* Wd     = (const float*)d_in[7];
    const float* bd     = (const float*)d_in[8];
    float* out = (float*)d_out;

    const int B = in_sizes[0] / TSTEPS;
    const int grid = (B + 127) / 128;  // 128 batch rows per 256-thread block
    lstm_feedback_mfma12<<<grid, 256, 0, stream>>>(
        inputs, Wk_w, Uk_w, b_w, Wk_d, Uk_d, b_d, Wd, bd, out, B);
}

// Round 15
// 410.300 us; speedup vs baseline: 1.1061x; 1.0239x over previous
//
#include <hip/hip_runtime.h>

#define TSTEPS 48
#define OUT_STEPS 24
#define L2E 1.44269504088896340736f
#define ECLAMP 30.0f

typedef short bf16x8 __attribute__((ext_vector_type(8)));
typedef float f32x16 __attribute__((ext_vector_type(16)));
typedef unsigned int u32x4 __attribute__((ext_vector_type(4)));

// RNE bf16 hi + truncated-residual lo (weights; off hot path).
__device__ __forceinline__ void bf_split_rne(float f, short& hi, short& lo) {
    unsigned u = __builtin_bit_cast(unsigned, f);
    unsigned r = u + 0x7FFFu + ((u >> 16) & 1u);
    unsigned short hb = (unsigned short)(r >> 16);
    float hif = __builtin_bit_cast(float, (unsigned)hb << 16);
    float lof = f - hif;
    unsigned short lb = (unsigned short)(__builtin_bit_cast(unsigned, lof) >> 16);
    hi = (short)hb; lo = (short)lb;
}

// Truncation split packed into one dword: low16 = hi-bf16, high16 = lo-bf16.
__device__ __forceinline__ unsigned split_pack(float f) {
    unsigned u = __builtin_bit_cast(unsigned, f);
    float hif = __builtin_bit_cast(float, u & 0xFFFF0000u);
    float lof = f - hif;
    unsigned lo = __builtin_bit_cast(unsigned, lof);
    return (u >> 16) | (lo & 0xFFFF0000u);
}

// Gate pre-scale for exp2: i,f,o -> -log2e; g (gate 2) -> -2*log2e.
__device__ __forceinline__ float gate_scale(int g) {
    return (g == 2) ? (-2.0f * L2E) : (-L2E);
}

// U-frag LDS slot: ((cell*4+g)*2+c)*2+hl, address (slot*64+lane)*16B.
// Lane-contiguous b128 reads/writes — the m97 fast path, conflict-free.
__device__ __forceinline__ int uslot(int cell, int g, int c, int hl) {
    return ((cell * 4 + g) * 2 + c) * 2 + hl;
}

// One LSTM step for 32 batch rows. h enters/exits as two K-half B-frags
// (identity repack — R12-verified). U-frags + A4 read from LDS each step
// (shared by all 4 waves; zero VALU cost; frees 64 arch VGPRs for occupancy).
// Activation math VERBATIM from the verified scalar form (absmax 4.88e-4).
template <bool NEED_P>
__device__ __forceinline__ float lstm_step32(unsigned xpack,
    const short* __restrict__ ufbase,          // &uflds[cell-base]
    const short* __restrict__ a4cell,          // &a4lds[cell][0][0]
    bf16x8& B0h, bf16x8& B0l, bf16x8& B1h, bf16x8& B1l,
    float* cs, const float* __restrict__ wdp,  // &wdlds[H][0] (broadcast)
    int lane, int H) {
    // B4 on H==0 lanes: [x_hi, x_lo, x_hi, 1, 1, 0,0,0].
    unsigned w0 = xpack;
    unsigned w1 = (xpack & 0xFFFFu) | 0x3F800000u;
    unsigned w2 = 0x00003F80u;
    if (H != 0) { w0 = 0u; w1 = 0u; w2 = 0u; }
    u32x4 b4u = {w0, w1, w2, 0u};
    const bf16x8 B4 = __builtin_bit_cast(bf16x8, b4u);
    const f32x16 zero16 = {0,0,0,0,0,0,0,0,0,0,0,0,0,0,0,0};

    f32x16 acc[4];
#pragma unroll
    for (int g = 0; g < 4; ++g) {
        const bf16x8 A4g = *(const bf16x8*)(a4cell + (g * 64 + lane) * 8);
        const bf16x8 Ah0 = *(const bf16x8*)(ufbase + (uslot(0, g, 0, 0) * 64 + lane) * 8);
        const bf16x8 Al0 = *(const bf16x8*)(ufbase + (uslot(0, g, 0, 1) * 64 + lane) * 8);
        const bf16x8 Ah1 = *(const bf16x8*)(ufbase + (uslot(0, g, 1, 0) * 64 + lane) * 8);
        const bf16x8 Al1 = *(const bf16x8*)(ufbase + (uslot(0, g, 1, 1) * 64 + lane) * 8);
        f32x16 a = __builtin_amdgcn_mfma_f32_32x32x16_bf16(A4g, B4, zero16, 0, 0, 0);
        a = __builtin_amdgcn_mfma_f32_32x32x16_bf16(Al0, B0h, a, 0, 0, 0);
        a = __builtin_amdgcn_mfma_f32_32x32x16_bf16(Ah0, B0l, a, 0, 0, 0);
        a = __builtin_amdgcn_mfma_f32_32x32x16_bf16(Ah0, B0h, a, 0, 0, 0);
        a = __builtin_amdgcn_mfma_f32_32x32x16_bf16(Al1, B1h, a, 0, 0, 0);
        a = __builtin_amdgcn_mfma_f32_32x32x16_bf16(Ah1, B1l, a, 0, 0, 0);
        a = __builtin_amdgcn_mfma_f32_32x32x16_bf16(Ah1, B1h, a, 0, 0, 0);
        acc[g] = a;
    }

    float pp = 0.0f;
    bf16x8 n0h, n0l, n1h, n1l;
#pragma unroll
    for (int r = 0; r < 16; ++r) {
        float ei = __builtin_amdgcn_exp2f(acc[0][r]);
        float ef = __builtin_amdgcn_exp2f(acc[1][r]);
        float eg = __builtin_amdgcn_exp2f(__builtin_fminf(acc[2][r], ECLAMP));
        float eo = __builtin_amdgcn_exp2f(acc[3][r]);
        float di = 1.0f + ei, df = 1.0f + ef, dg = 1.0f + eg, do_ = 1.0f + eo;
        float ngs = __builtin_fmaf(eg, 2.0f * L2E, -2.0f * L2E);  // -2L2E*(1-eg)
        float t1 = di * dg;
        float t2 = cs[r] * t1;
        float num = __builtin_fmaf(ngs, df, t2);
        float cn = num * __builtin_amdgcn_rcpf(df * t1);          // scaled c'
        cs[r] = cn;
        float ec = __builtin_amdgcn_exp2f(__builtin_fminf(cn, ECLAMP)); // e^-2c
        float h = (1.0f - ec) * __builtin_amdgcn_rcpf(do_ * (1.0f + ec)); // o*tanh(c)
        if constexpr (NEED_P) pp = __builtin_fmaf(h, wdp[r], pp); // LDS broadcast
        unsigned u = __builtin_bit_cast(unsigned, h);
        float hif = __builtin_bit_cast(float, u & 0xFFFF0000u);
        float lof = h - hif;
        short hb = (short)(u >> 16);
        short lb = (short)(__builtin_bit_cast(unsigned, lof) >> 16);
        if (r < 8) { n0h[r] = hb; n0l[r] = lb; }
        else       { n1h[r - 8] = hb; n1l[r - 8] = lb; }
    }
    B0h = n0h; B0l = n0l; B1h = n1h; B1l = n1l;
    return pp;
}

// (256,3): U-frags in LDS free 64 arch VGPRs -> ~140 total/wave -> 3 waves/SIMD
// (vs 2 before). Same instruction stream as R14's best; the extra wave fills
// the 32% VALU idle (dependent MFMA->trans chains).
__global__ __launch_bounds__(256, 3) void lstm_feedback_mfma13(
    const float* __restrict__ inputs,  // [B, 48]
    const float* __restrict__ Wk_w, const float* __restrict__ Uk_w, const float* __restrict__ b_w,
    const float* __restrict__ Wk_d, const float* __restrict__ Uk_d, const float* __restrict__ b_d,
    const float* __restrict__ Wd, const float* __restrict__ bd,
    float* __restrict__ out,           // [B, 24]
    int B) {
    const int tid = threadIdx.x;       // 4 waves x 32 batch = 128 batch/block
    const int w = tid >> 6;
    const int lane = tid & 63;
    const int m = lane & 31;           // batch column within wave / out-unit row
    const int H = lane >> 5;
    const int mblk = blockIdx.x * 128;
    const long row = (long)(mblk + w * 32 + m);

    __shared__ __align__(16) short uflds[32 * 64 * 8];     // 32 KB: both cells' U-frags
    __shared__ __align__(16) short a4lds[2 * 4 * 64 * 8];  // 8 KB: both cells' A4
    __shared__ float wdlds[2][16];                         // Wd in D-reg order

    // Waves 0/1 stage cell 0/1: U-frags (pre-scaled, permuted, hi/lo split).
    if (w < 2) {
        const float* Uks = w ? Uk_d : Uk_w;
        const float* Wks = w ? Wk_d : Wk_w;
        const float* bvs = w ? b_d : b_w;
#pragma unroll
        for (int g = 0; g < 4; ++g) {
            const float s = gate_scale(g);
#pragma unroll
            for (int c = 0; c < 2; ++c) {
                bf16x8 ah, al;
#pragma unroll
                for (int j = 0; j < 8; ++j) {
                    const int uin = 16 * c + 4 * H + (j & 3) + 8 * (j >> 2);
                    float wt = Uks[uin * 128 + g * 32 + m] * s;
                    short hb, lb; bf_split_rne(wt, hb, lb);
                    ah[j] = hb; al[j] = lb;
                }
                *(bf16x8*)(uflds + (uslot(w, g, c, 0) * 64 + lane) * 8) = ah;
                *(bf16x8*)(uflds + (uslot(w, g, c, 1) * 64 + lane) * 8) = al;
            }
            // A4: [wk_hi, wk_hi, wk_lo, b_hi, b_lo, 0,0,0] on H==0 lanes, else 0.
            short whi, wlo, bhi, blo;
            bf_split_rne(Wks[g * 32 + m] * s, whi, wlo);
            bf_split_rne(bvs[g * 32 + m] * s, bhi, blo);
            bf16x8 a = {whi, whi, wlo, bhi, blo, 0, 0, 0};
            u32x4 z4 = {0u, 0u, 0u, 0u};
            if (H != 0) a = __builtin_bit_cast(bf16x8, z4);
            *(bf16x8*)(a4lds + ((w * 4 + g) * 64 + lane) * 8) = a;
        }
    }
    // Wd in D-layout order: unit of D reg r is (r&3) + 8*(r>>2) + 4H.
    if (tid < 32) {
        const int r = tid & 15, Hh = tid >> 4;
        wdlds[Hh][r] = Wd[(r & 3) + 8 * (r >> 2) + 4 * Hh];
    }

    u32x4 z4 = {0u, 0u, 0u, 0u};
    bf16x8 B0h = __builtin_bit_cast(bf16x8, z4), B0l = B0h, B1h = B0h, B1l = B0h;
    float cs[16];
#pragma unroll
    for (int r = 0; r < 16; ++r) cs[r] = 0.0f;

    __syncthreads();  // uflds + a4lds + wdlds visible

    const short* __restrict__ uf_w = uflds;
    const short* __restrict__ uf_d = uflds + 16 * 64 * 8;
    const short* __restrict__ a4_w = a4lds;
    const short* __restrict__ a4_d = a4lds + 4 * 64 * 8;
    const float* __restrict__ wdp = &wdlds[H][0];

    // ---- warmup: per-lane x from global (L2-resident), one-step prefetch ----
    float xc = inputs[row * TSTEPS + 0];
    for (int t = 0; t < TSTEPS - 1; ++t) {
        float xn = inputs[row * TSTEPS + t + 1];  // issued before the step body
        asm volatile("" ::: "memory");  // keep LDS frag reads in-loop (anti-LICM)
        lstm_step32<false>(split_pack(xc), uf_w, a4_w,
                           B0h, B0l, B1h, B1l, cs, wdp, lane, H);
        xc = xn;
    }

    const float bdv = bd[0];

    // ---- last warmup step with pred fold; single-shuffle reduce ----
    asm volatile("" ::: "memory");
    float p = lstm_step32<true>(split_pack(xc), uf_w, a4_w,
                                B0h, B0l, B1h, B1l, cs, wdp, lane, H);
    p += __shfl_xor(p, 32);
    p += bdv;                          // both H lanes of batch m hold pred(batch m)
    if (H == 0) out[row * OUT_STEPS + 0] = p;

    // ---- decode: pointer swap only (no reload, no transition spill) ----
    for (int s = 1; s < OUT_STEPS; ++s) {
        asm volatile("" ::: "memory");
        p = lstm_step32<true>(split_pack(p), uf_d, a4_d,
                              B0h, B0l, B1h, B1l, cs, wdp, lane, H);
        p += __shfl_xor(p, 32);
        p += bdv;
        if (H == 0) out[row * OUT_STEPS + s] = p;
    }
}

extern "C" void kernel_launch(void* const* d_in, const int* in_sizes, int n_in,
                              void* d_out, int out_size, void* d_ws, size_t ws_size,
                              hipStream_t stream) {
    const float* inputs = (const float*)d_in[0];
    const float* Wk_w   = (const float*)d_in[1];
    const float* Uk_w   = (const float*)d_in[2];
    const float* b_w    = (const float*)d_in[3];
    const float* Wk_d   = (const float*)d_in[4];
    const float* Uk_d   = (const float*)d_in[5];
    const float* b_d    = (const float*)d_in[6];
    const float* Wd     = (const float*)d_in[7];
    const float* bd     = (const float*)d_in[8];
    float* out = (float*)d_out;

    const int B = in_sizes[0] / TSTEPS;
    const int grid = (B + 127) / 128;  // 128 batch rows per 256-thread block
    lstm_feedback_mfma13<<<grid, 256, 0, stream>>>(
        inputs, Wk_w, Uk_w, b_w, Wk_d, Uk_d, b_d, Wd, bd, out, B);
}